// Round 1
// 505.158 us; speedup vs baseline: 1.0050x; 1.0050x over previous
//
#include <hip/hip_runtime.h>

typedef short short8 __attribute__((ext_vector_type(8)));
typedef float f32x4 __attribute__((ext_vector_type(4)));
typedef unsigned short ushort;

#define MFMA(a, b, c) __builtin_amdgcn_mfma_f32_16x16x32_bf16(a, b, c, 0, 0, 0)

// ---- ws layout (ushort element offsets) ---- (unchanged; fragment-packed weights)
#define WS_WQT 0        // 18 frags (nt*3+kt)
#define WS_WKT 9216     // 36 frags (kt6*6+nt)
#define WS_WVT 27648    // 36 frags (kt6*6+nt)
#define WS_WOT 46080    // 18 frags (nt*3+kt)
#define WS_BIAS 55296   // bias table bf16 [225*6]
#define WS_TOTAL 56646

// ---- LDS layout (ushort offsets), total 39052 B -> 4 blocks/CU ----
// A region roles over time: A_q -> A_kv0 -> A_kv1 -> K16'[tok][h*16+d] -> obuf[tok][h*16+d]
#define STR_A 104
#define U_A    0        // 64*104          = 6656 ushorts
#define U_VT   6656     // [6][16][72]     = 6912
#define STR_VT 72
#define U_PS   13568    // 4 waves * 1152 (ps stride 72 x 16 rows; qsc aliased at base, stride 24)
#define U_BIAS 18176    // 1350
#define U_TOTAL 19526   // = 39052 bytes

// DPP cross-lane (within 16-lane row == quad group): VALU pipe, no LDS latency
#define DPP_F(v, ctrl) __int_as_float(__builtin_amdgcn_update_dpp(0, __float_as_int(v), ctrl, 0xF, 0xF, true))

__device__ __forceinline__ ushort f2bf(float x) {
    unsigned u = __float_as_uint(x);
    u = (u + 0x7FFFu + ((u >> 16) & 1u)) >> 16;   // RNE
    return (ushort)u;
}
__device__ __forceinline__ float bf2f(ushort u) {
    return __uint_as_float(((unsigned)u) << 16);
}

__global__ void prep_weights(const float* __restrict__ Wq, const float* __restrict__ Wk,
                             const float* __restrict__ Wv, const float* __restrict__ Wo,
                             const float* __restrict__ btab, ushort* __restrict__ ws) {
    int idx = blockIdx.x * 256 + threadIdx.x;
    if (idx < WS_WKT) {                         // WqT packed, frag = nt*3+kt
        int f = idx >> 9, w = idx & 511, lane = w >> 3, j = w & 7;
        int nt = f / 3, kt = f % 3;
        int n = nt * 16 + (lane & 15), k = kt * 32 + (lane >> 4) * 8 + j;
        ws[idx] = f2bf(Wq[k * 96 + n]);
    } else if (idx < WS_WVT) {                  // WkT packed, frag = kt6*6+nt
        int t = idx - WS_WKT;
        int f = t >> 9, w = t & 511, lane = w >> 3, j = w & 7;
        int kt6 = f / 6, nt = f % 6;
        int n = nt * 16 + (lane & 15), k = kt6 * 32 + (lane >> 4) * 8 + j;
        ws[idx] = f2bf(Wk[k * 96 + n]);
    } else if (idx < WS_WOT) {                  // WvT packed, frag = kt6*6+nt
        int t = idx - WS_WVT;
        int f = t >> 9, w = t & 511, lane = w >> 3, j = w & 7;
        int kt6 = f / 6, nt = f % 6;
        int n = nt * 16 + (lane & 15), k = kt6 * 32 + (lane >> 4) * 8 + j;
        ws[idx] = f2bf(Wv[k * 96 + n]);
    } else if (idx < WS_BIAS) {                 // WoT packed, frag = nt*3+kt
        int t = idx - WS_WOT;
        int f = t >> 9, w = t & 511, lane = w >> 3, j = w & 7;
        int nt = f / 3, kt = f % 3;
        int n = nt * 16 + (lane & 15), k = kt * 32 + (lane >> 4) * 8 + j;
        ws[idx] = f2bf(Wo[k * 96 + n]);
    } else if (idx < WS_TOTAL) {                // bias table -> bf16
        ws[idx] = f2bf(btab[idx - WS_BIAS]);
    }
}

__global__ __launch_bounds__(256, 4) void swin_attn(
    const float* __restrict__ xq, const float* __restrict__ xkv,
    const float* __restrict__ bq, const float* __restrict__ bk,
    const float* __restrict__ bv, const float* __restrict__ bo,
    const ushort* __restrict__ ws, float* __restrict__ out)
{
    __shared__ __align__(16) ushort smem[U_TOTAL + 8];
    const int tid = threadIdx.x;
    const int wave = tid >> 6, lane = tid & 63;
    const int l15 = lane & 15, quad = lane >> 4;
    int wid = ((blockIdx.x & 7) << 9) | (blockIdx.x >> 3);   // XCD swizzle
    const int b = wid >> 10;
    const int wh = (wid >> 5) & 31, ww = wid & 31;
    const int h0 = wh * 8, w0 = ww * 8;
    const int mt = wave;                     // each wave owns one 16-token M-tile

    ushort* A     = smem + U_A;
    ushort* vt    = smem + U_VT;
    ushort* ps    = smem + U_PS + wave * 1152;   // wave-private P (stride 72, 16 rows)
    ushort* qsc   = ps;                          // aliased: consumed before ps rows written
    ushort* biasl = smem + U_BIAS;

    // per-lane projection biases (coalesced, L2-hot)
    float bqr[6], bkr[6], bvr[6];
    #pragma unroll
    for (int h = 0; h < 6; ++h) {
        bqr[h] = bq[h * 16 + l15]; bkr[h] = bk[h * 16 + l15]; bvr[h] = bv[h * 16 + l15];
    }

    // staging decomposition: p = tid + t*256 over 768 (c,i) rows; c = p%96, i = p/96
    int pc[3], pi[3];
    #pragma unroll
    for (int t = 0; t < 3; ++t) { int p = tid + t * 256; pc[t] = p % 96; pi[t] = p / 96; }

    // ---- phase 0: issue xq loads, stage bias table, write A_q ----
    const float* xqb = xq + (size_t)b * 96 * 65536;
    float4 pf[3][2];
    #pragma unroll
    for (int t = 0; t < 3; ++t) {
        const float* g = xqb + (size_t)pc[t] * 65536 + (h0 + pi[t]) * 256 + w0;
        pf[t][0] = *(const float4*)g; pf[t][1] = *(const float4*)(g + 4);
    }
    for (int i = tid; i < 1350; i += 256) biasl[i] = ws[WS_BIAS + i];

    #pragma unroll
    for (int t = 0; t < 3; ++t) {
        int base = (pi[t] * 8) * STR_A + pc[t];
        A[base]             = f2bf(pf[t][0].x); A[base + STR_A]     = f2bf(pf[t][0].y);
        A[base + 2 * STR_A] = f2bf(pf[t][0].z); A[base + 3 * STR_A] = f2bf(pf[t][0].w);
        A[base + 4 * STR_A] = f2bf(pf[t][1].x); A[base + 5 * STR_A] = f2bf(pf[t][1].y);
        A[base + 6 * STR_A] = f2bf(pf[t][1].z); A[base + 7 * STR_A] = f2bf(pf[t][1].w);
    }
    __syncthreads();   // B1: A_q visible

    // ---- phase 1: issue kv half0 loads; q-projection for ALL heads (hoisted) ----
    const float* xkvb = xkv + (size_t)b * 192 * 65536;
    float4 pg[3][2];
    #pragma unroll
    for (int t = 0; t < 3; ++t) {
        const float* g = xkvb + (size_t)pc[t] * 65536 + (h0 + pi[t]) * 256 + w0;
        pg[t][0] = *(const float4*)g; pg[t][1] = *(const float4*)(g + 4);
    }

    const int arow = (mt * 16 + l15) * STR_A + quad * 8;
    short8 a0 = *(const short8*)(A + arow);
    short8 a1 = *(const short8*)(A + arow + 32);
    short8 a2 = *(const short8*)(A + arow + 64);
    unsigned qpk[12];   // q (scaled, biased) as packed bf16 pairs: 12 VGPRs instead of 24
    #pragma unroll
    for (int h = 0; h < 6; ++h) {
        f32x4 qa = {bqr[h], bqr[h], bqr[h], bqr[h]};   // bias as MFMA C-seed
        qa = MFMA(a0, *(const short8*)(ws + WS_WQT + ((h * 3 + 0) * 64 + lane) * 8), qa);
        qa = MFMA(a1, *(const short8*)(ws + WS_WQT + ((h * 3 + 1) * 64 + lane) * 8), qa);
        qa = MFMA(a2, *(const short8*)(ws + WS_WQT + ((h * 3 + 2) * 64 + lane) * 8), qa);
        qpk[h * 2]     = (unsigned)f2bf(qa[0] * 0.25f) | ((unsigned)f2bf(qa[1] * 0.25f) << 16);
        qpk[h * 2 + 1] = (unsigned)f2bf(qa[2] * 0.25f) | ((unsigned)f2bf(qa[3] * 0.25f) << 16);
    }
    __syncthreads();   // B2: all A_q reads done

    // ---- phase 2: kv half0 stage + MFMA ----
    #pragma unroll
    for (int t = 0; t < 3; ++t) {
        int base = (pi[t] * 8) * STR_A + pc[t];
        A[base]             = f2bf(pg[t][0].x); A[base + STR_A]     = f2bf(pg[t][0].y);
        A[base + 2 * STR_A] = f2bf(pg[t][0].z); A[base + 3 * STR_A] = f2bf(pg[t][0].w);
        A[base + 4 * STR_A] = f2bf(pg[t][1].x); A[base + 5 * STR_A] = f2bf(pg[t][1].y);
        A[base + 6 * STR_A] = f2bf(pg[t][1].z); A[base + 7 * STR_A] = f2bf(pg[t][1].w);
    }
    __syncthreads();   // B3: A_kv0 visible

    // issue kv half1 loads (overlap half0 compute)
    #pragma unroll
    for (int t = 0; t < 3; ++t) {
        const float* g = xkvb + (size_t)(96 + pc[t]) * 65536 + (h0 + pi[t]) * 256 + w0;
        pf[t][0] = *(const float4*)g; pf[t][1] = *(const float4*)(g + 4);
    }

    f32x4 accK[6], accV[6];
    #pragma unroll
    for (int n = 0; n < 6; ++n) {              // biases as MFMA C-seed
        accK[n] = {bkr[n], bkr[n], bkr[n], bkr[n]};
        accV[n] = {bvr[n], bvr[n], bvr[n], bvr[n]};
    }
    #pragma unroll
    for (int kt = 0; kt < 3; ++kt) {
        short8 a = *(const short8*)(A + arow + kt * 32);
        #pragma unroll
        for (int nt = 0; nt < 6; ++nt) {
            short8 bk8 = *(const short8*)(ws + WS_WKT + (((kt * 6) + nt) * 64 + lane) * 8);
            accK[nt] = MFMA(a, bk8, accK[nt]);
            short8 bv8 = *(const short8*)(ws + WS_WVT + (((kt * 6) + nt) * 64 + lane) * 8);
            accV[nt] = MFMA(a, bv8, accV[nt]);
        }
    }
    __syncthreads();   // B4: all A_kv0 reads done

    #pragma unroll
    for (int t = 0; t < 3; ++t) {
        int base = (pi[t] * 8) * STR_A + pc[t];
        A[base]             = f2bf(pf[t][0].x); A[base + STR_A]     = f2bf(pf[t][0].y);
        A[base + 2 * STR_A] = f2bf(pf[t][0].z); A[base + 3 * STR_A] = f2bf(pf[t][0].w);
        A[base + 4 * STR_A] = f2bf(pf[t][1].x); A[base + 5 * STR_A] = f2bf(pf[t][1].y);
        A[base + 6 * STR_A] = f2bf(pf[t][1].z); A[base + 7 * STR_A] = f2bf(pf[t][1].w);
    }
    __syncthreads();   // B5: A_kv1 visible

    #pragma unroll
    for (int kt = 0; kt < 3; ++kt) {
        short8 a = *(const short8*)(A + arow + kt * 32);
        #pragma unroll
        for (int nt = 0; nt < 6; ++nt) {
            short8 bk8 = *(const short8*)(ws + WS_WKT + ((((3 + kt) * 6) + nt) * 64 + lane) * 8);
            accK[nt] = MFMA(a, bk8, accK[nt]);
            short8 bv8 = *(const short8*)(ws + WS_WVT + ((((3 + kt) * 6) + nt) * 64 + lane) * 8);
            accV[nt] = MFMA(a, bv8, accV[nt]);
        }
    }
    // K16' into A region (own rows: self-ordered after own A reads) + VT (own cols, fresh region)
    #pragma unroll
    for (int nt = 0; nt < 6; ++nt) {
        ushort* dk = A + (mt * 16 + quad * 4) * STR_A + nt * 16 + l15;
        ushort* dv = vt + nt * (16 * STR_VT) + l15 * STR_VT + (mt * 16 + quad * 4);
        #pragma unroll
        for (int r = 0; r < 4; ++r) {
            dk[r * STR_A] = f2bf(accK[nt][r]);
            dv[r]         = f2bf(accV[nt][r]);
        }
    }
    __syncthreads();   // B6: K16' + VT visible

    // ---- rel-bias indices (head-independent) ----
    const int qtok0 = mt * 16 + quad * 4;
    int bidx[4][4];
    #pragma unroll
    for (int nt = 0; nt < 4; ++nt) {
        int kt2 = nt * 16 + l15, i2 = kt2 >> 3, j2 = kt2 & 7;
        #pragma unroll
        for (int r = 0; r < 4; ++r) {
            int qt = qtok0 + r, i1 = qt >> 3, j1 = qt & 7;
            bidx[nt][r] = ((i1 - i2 + 7) * 15 + (j1 - j2 + 7)) * 6;
        }
    }

    // ---- per-head: S = q k^T (+bias via C-seed) -> softmax (DPP) -> P v ----
    f32x4 accO[6];
    short8 zero8 = {};
    #pragma unroll
    for (int h = 0; h < 6; ++h) {
        asm volatile("" ::: "memory");   // keep DS program order across qsc/ps alias
        unsigned wlo = qpk[h * 2], whi = qpk[h * 2 + 1];
        qsc[(quad * 4 + 0) * 24 + l15] = (ushort)wlo;
        qsc[(quad * 4 + 1) * 24 + l15] = (ushort)(wlo >> 16);
        qsc[(quad * 4 + 2) * 24 + l15] = (ushort)whi;
        qsc[(quad * 4 + 3) * 24 + l15] = (ushort)(whi >> 16);
        short8 aq = zero8;
        if (quad < 2) aq = *(const short8*)(qsc + l15 * 24 + quad * 8);
        f32x4 s[4];
        #pragma unroll
        for (int nt = 0; nt < 4; ++nt) {
            short8 bk8 = zero8;
            if (quad < 2) bk8 = *(const short8*)(A + (nt * 16 + l15) * STR_A + h * 16 + quad * 8);
            f32x4 c;
            c[0] = bf2f(biasl[bidx[nt][0] + h]); c[1] = bf2f(biasl[bidx[nt][1] + h]);
            c[2] = bf2f(biasl[bidx[nt][2] + h]); c[3] = bf2f(biasl[bidx[nt][3] + h]);
            s[nt] = MFMA(aq, bk8, c);
        }
        // row softmax within 16-lane quad group — DPP (VALU pipe, no LDS latency)
        float pr[4][4];
        #pragma unroll
        for (int r = 0; r < 4; ++r) {
            float m = fmaxf(fmaxf(s[0][r], s[1][r]), fmaxf(s[2][r], s[3][r]));
            m = fmaxf(m, DPP_F(m, 0xB1));    // quad_perm xor 1
            m = fmaxf(m, DPP_F(m, 0x4E));    // quad_perm xor 2
            m = fmaxf(m, DPP_F(m, 0x124));   // row_ror:4
            m = fmaxf(m, DPP_F(m, 0x128));   // row_ror:8
            float l = 0.f;
            #pragma unroll
            for (int nt = 0; nt < 4; ++nt) { pr[nt][r] = __expf(s[nt][r] - m); l += pr[nt][r]; }
            l += DPP_F(l, 0xB1); l += DPP_F(l, 0x4E);
            l += DPP_F(l, 0x124); l += DPP_F(l, 0x128);
            float inv = __builtin_amdgcn_rcpf(l);
            #pragma unroll
            for (int nt = 0; nt < 4; ++nt) pr[nt][r] *= inv;
        }
        // C-layout -> A-layout via wave-private LDS
        #pragma unroll
        for (int nt = 0; nt < 4; ++nt)
            #pragma unroll
            for (int r = 0; r < 4; ++r)
                ps[(quad * 4 + r) * 72 + nt * 16 + l15] = f2bf(pr[nt][r]);
        f32x4 o = {};
        #pragma unroll
        for (int k2 = 0; k2 < 2; ++k2) {
            short8 ap  = *(const short8*)(ps + l15 * 72 + k2 * 32 + quad * 8);
            short8 bv8 = *(const short8*)(vt + h * (16 * STR_VT) + l15 * STR_VT + k2 * 32 + quad * 8);
            o = MFMA(ap, bv8, o);
        }
        accO[h] = o;
    }
    __syncthreads();   // B7: all K16' reads done before A-region reuse as obuf

    // ---- concat heads into obuf (own-wave rows) + out projection + store ----
    float bor_[6];
    #pragma unroll
    for (int h = 0; h < 6; ++h) bor_[h] = bo[h * 16 + l15];
    ushort* obuf = A;
    #pragma unroll
    for (int h = 0; h < 6; ++h)
        #pragma unroll
        for (int r = 0; r < 4; ++r)
            obuf[(mt * 16 + quad * 4 + r) * STR_A + h * 16 + l15] = f2bf(accO[h][r]);

    {
        int t0 = mt * 16 + quad * 4;
        int i = t0 >> 3, j0 = t0 & 7;
        #pragma unroll
        for (int nt = 0; nt < 6; ++nt) {
            f32x4 acc = {bor_[nt], bor_[nt], bor_[nt], bor_[nt]};   // bias as C-seed
            #pragma unroll
            for (int kt = 0; kt < 3; ++kt) {
                short8 a  = *(const short8*)(obuf + arow + kt * 32);
                short8 bb = *(const short8*)(ws + WS_WOT + ((nt * 3 + kt) * 64 + lane) * 8);
                acc = MFMA(a, bb, acc);
            }
            int cout = nt * 16 + l15;
            float4 v4 = make_float4(acc[0], acc[1], acc[2], acc[3]);
            float* dst = out + (size_t)(b * 96 + cout) * 65536 + (h0 + i) * 256 + w0 + j0;
            *(float4*)dst = v4;
        }
    }
}

extern "C" void kernel_launch(void* const* d_in, const int* in_sizes, int n_in,
                              void* d_out, int out_size, void* d_ws, size_t ws_size,
                              hipStream_t stream) {
    const float* xq   = (const float*)d_in[0];
    const float* xkv  = (const float*)d_in[1];
    const float* Wq   = (const float*)d_in[2];
    const float* bq   = (const float*)d_in[3];
    const float* Wk   = (const float*)d_in[4];
    const float* bk   = (const float*)d_in[5];
    const float* Wv   = (const float*)d_in[6];
    const float* bv   = (const float*)d_in[7];
    const float* btab = (const float*)d_in[8];
    const float* Wo   = (const float*)d_in[9];
    const float* bo   = (const float*)d_in[10];
    ushort* ws = (ushort*)d_ws;
    float* out = (float*)d_out;

    hipLaunchKernelGGL(prep_weights, dim3((WS_TOTAL + 255) / 256), dim3(256), 0, stream,
                       Wq, Wk, Wv, Wo, btab, ws);
    hipLaunchKernelGGL(swin_attn, dim3(4096), dim3(256), 0, stream,
                       xq, xkv, bq, bk, bv, bo, ws, out);
}

// Round 2
// 485.657 us; speedup vs baseline: 1.0453x; 1.0402x over previous
//
#include <hip/hip_runtime.h>

typedef short short8 __attribute__((ext_vector_type(8)));
typedef float f32x4 __attribute__((ext_vector_type(4)));
typedef unsigned short ushort;

#define MFMA(a, b, c) __builtin_amdgcn_mfma_f32_16x16x32_bf16(a, b, c, 0, 0, 0)

// ---- ws layout (ushort element offsets) ---- (fragment-packed weights)
#define WS_WQT 0        // 18 frags (nt*3+kt)
#define WS_WKT 9216     // 36 frags (kt6*6+nt)
#define WS_WVT 27648    // 36 frags (kt6*6+nt)
#define WS_WOT 46080    // 18 frags (nt*3+kt)
#define WS_BIAS 55296   // bias table bf16 [225*6], PRE-SCALED by log2(e)
#define WS_TOTAL 56646

// ---- LDS layout (ushort offsets), total 39052 B -> 4 blocks/CU ----
// A region roles: A_q -> A_kv0 -> A_kv1 -> K16'[tok][h*16+d] -> obuf[tok][h*16+d]
#define STR_A 104
#define U_A    0        // 64*104          = 6656 ushorts
#define U_VT   6656     // [6][16][72]     = 6912
#define STR_VT 72
#define U_PS   13568    // 4 waves * 1152 (ps stride 72 x 16 rows; qscA@0 / qscB@384, stride 24)
#define U_BIAS 18176    // 1350
#define U_TOTAL 19526   // = 39052 bytes

#define LOG2E 1.44269504f

// DPP cross-lane (within 16-lane row): VALU pipe, no LDS latency
#define DPP_F(v, ctrl) __int_as_float(__builtin_amdgcn_update_dpp(0, __float_as_int(v), ctrl, 0xF, 0xF, true))

__device__ __forceinline__ ushort f2bf(float x) {
    unsigned u = __float_as_uint(x);
    u = (u + 0x7FFFu + ((u >> 16) & 1u)) >> 16;   // RNE
    return (ushort)u;
}
__device__ __forceinline__ float bf2f(ushort u) {
    return __uint_as_float(((unsigned)u) << 16);
}

__global__ void prep_weights(const float* __restrict__ Wq, const float* __restrict__ Wk,
                             const float* __restrict__ Wv, const float* __restrict__ Wo,
                             const float* __restrict__ btab, ushort* __restrict__ ws) {
    int idx = blockIdx.x * 256 + threadIdx.x;
    if (idx < WS_WKT) {                         // WqT packed, frag = nt*3+kt
        int f = idx >> 9, w = idx & 511, lane = w >> 3, j = w & 7;
        int nt = f / 3, kt = f % 3;
        int n = nt * 16 + (lane & 15), k = kt * 32 + (lane >> 4) * 8 + j;
        ws[idx] = f2bf(Wq[k * 96 + n]);
    } else if (idx < WS_WVT) {                  // WkT packed, frag = kt6*6+nt
        int t = idx - WS_WKT;
        int f = t >> 9, w = t & 511, lane = w >> 3, j = w & 7;
        int kt6 = f / 6, nt = f % 6;
        int n = nt * 16 + (lane & 15), k = kt6 * 32 + (lane >> 4) * 8 + j;
        ws[idx] = f2bf(Wk[k * 96 + n]);
    } else if (idx < WS_WOT) {                  // WvT packed, frag = kt6*6+nt
        int t = idx - WS_WVT;
        int f = t >> 9, w = t & 511, lane = w >> 3, j = w & 7;
        int kt6 = f / 6, nt = f % 6;
        int n = nt * 16 + (lane & 15), k = kt6 * 32 + (lane >> 4) * 8 + j;
        ws[idx] = f2bf(Wv[k * 96 + n]);
    } else if (idx < WS_BIAS) {                 // WoT packed, frag = nt*3+kt
        int t = idx - WS_WOT;
        int f = t >> 9, w = t & 511, lane = w >> 3, j = w & 7;
        int nt = f / 3, kt = f % 3;
        int n = nt * 16 + (lane & 15), k = kt * 32 + (lane >> 4) * 8 + j;
        ws[idx] = f2bf(Wo[k * 96 + n]);
    } else if (idx < WS_TOTAL) {                // bias table -> bf16, pre-scaled for exp2 softmax
        ws[idx] = f2bf(btab[idx - WS_BIAS] * LOG2E);
    }
}

__device__ __forceinline__ void softmax16(f32x4 (&s)[4], float (&pr)[4][4]) {
    #pragma unroll
    for (int r = 0; r < 4; ++r) {
        float m = fmaxf(fmaxf(s[0][r], s[1][r]), fmaxf(s[2][r], s[3][r]));
        m = fmaxf(m, DPP_F(m, 0xB1));    // quad_perm xor 1
        m = fmaxf(m, DPP_F(m, 0x4E));    // quad_perm xor 2
        m = fmaxf(m, DPP_F(m, 0x124));   // row_ror:4
        m = fmaxf(m, DPP_F(m, 0x128));   // row_ror:8
        float l = 0.f;
        #pragma unroll
        for (int nt = 0; nt < 4; ++nt) { pr[nt][r] = exp2f(s[nt][r] - m); l += pr[nt][r]; }
        l += DPP_F(l, 0xB1); l += DPP_F(l, 0x4E);
        l += DPP_F(l, 0x124); l += DPP_F(l, 0x128);
        float inv = __builtin_amdgcn_rcpf(l);
        #pragma unroll
        for (int nt = 0; nt < 4; ++nt) pr[nt][r] *= inv;
    }
}

__global__ __launch_bounds__(256, 4) void swin_attn(
    const float* __restrict__ xq, const float* __restrict__ xkv,
    const float* __restrict__ bq, const float* __restrict__ bk,
    const float* __restrict__ bv, const float* __restrict__ bo,
    const ushort* __restrict__ ws, float* __restrict__ out)
{
    __shared__ __align__(16) ushort smem[U_TOTAL + 8];
    const int tid = threadIdx.x;
    const int wave = tid >> 6, lane = tid & 63;
    const int l15 = lane & 15, quad = lane >> 4;
    int wid = ((blockIdx.x & 7) << 9) | (blockIdx.x >> 3);   // XCD swizzle
    const int b = wid >> 10;
    const int wh = (wid >> 5) & 31, ww = wid & 31;
    const int h0 = wh * 8, w0 = ww * 8;
    const int mt = wave;                     // each wave owns one 16-token M-tile

    ushort* A     = smem + U_A;
    ushort* vt    = smem + U_VT;
    ushort* ps    = smem + U_PS + wave * 1152;   // wave-private P (stride 72, 16 rows)
    ushort* biasl = smem + U_BIAS;

    // per-lane projection biases (coalesced, L2-hot)
    float bqr[6], bkr[6], bvr[6];
    #pragma unroll
    for (int h = 0; h < 6; ++h) {
        bqr[h] = bq[h * 16 + l15]; bkr[h] = bk[h * 16 + l15]; bvr[h] = bv[h * 16 + l15];
    }

    // staging decomposition: p = tid + t*256 over 768 (c,i) rows; c = p%96, i = p/96
    int pc[3], pi[3];
    #pragma unroll
    for (int t = 0; t < 3; ++t) { int p = tid + t * 256; pc[t] = p % 96; pi[t] = p / 96; }

    // ---- phase 0: issue xq loads, stage bias table, write A_q ----
    const float* xqb = xq + (size_t)b * 96 * 65536;
    float4 pf[3][2];
    #pragma unroll
    for (int t = 0; t < 3; ++t) {
        const float* g = xqb + (size_t)pc[t] * 65536 + (h0 + pi[t]) * 256 + w0;
        pf[t][0] = *(const float4*)g; pf[t][1] = *(const float4*)(g + 4);
    }
    for (int i = tid; i < 1350; i += 256) biasl[i] = ws[WS_BIAS + i];

    #pragma unroll
    for (int t = 0; t < 3; ++t) {
        int base = (pi[t] * 8) * STR_A + pc[t];
        A[base]             = f2bf(pf[t][0].x); A[base + STR_A]     = f2bf(pf[t][0].y);
        A[base + 2 * STR_A] = f2bf(pf[t][0].z); A[base + 3 * STR_A] = f2bf(pf[t][0].w);
        A[base + 4 * STR_A] = f2bf(pf[t][1].x); A[base + 5 * STR_A] = f2bf(pf[t][1].y);
        A[base + 6 * STR_A] = f2bf(pf[t][1].z); A[base + 7 * STR_A] = f2bf(pf[t][1].w);
    }
    __syncthreads();   // B1: A_q visible

    // ---- phase 1: issue kv half0 loads; q-projection for ALL heads (rotated weight loads) ----
    const float* xkvb = xkv + (size_t)b * 192 * 65536;
    float4 pg[3][2];
    #pragma unroll
    for (int t = 0; t < 3; ++t) {
        const float* g = xkvb + (size_t)pc[t] * 65536 + (h0 + pi[t]) * 256 + w0;
        pg[t][0] = *(const float4*)g; pg[t][1] = *(const float4*)(g + 4);
    }

    const int arow = (mt * 16 + l15) * STR_A + quad * 8;
    short8 a0 = *(const short8*)(A + arow);
    short8 a1 = *(const short8*)(A + arow + 32);
    short8 a2 = *(const short8*)(A + arow + 64);
    unsigned qpk[12];   // q (scaled by 2^-2 * log2e, biased) as packed bf16 pairs
    {
        short8 wq0 = *(const short8*)(ws + WS_WQT + ((0) * 64 + lane) * 8);
        short8 wq1 = *(const short8*)(ws + WS_WQT + ((1) * 64 + lane) * 8);
        short8 wq2 = *(const short8*)(ws + WS_WQT + ((2) * 64 + lane) * 8);
        #pragma unroll
        for (int h = 0; h < 6; ++h) {
            short8 c0 = wq0, c1 = wq1, c2 = wq2;
            if (h < 5) {   // rotate: issue next head's frags before this head's MFMAs
                wq0 = *(const short8*)(ws + WS_WQT + (((h + 1) * 3 + 0) * 64 + lane) * 8);
                wq1 = *(const short8*)(ws + WS_WQT + (((h + 1) * 3 + 1) * 64 + lane) * 8);
                wq2 = *(const short8*)(ws + WS_WQT + (((h + 1) * 3 + 2) * 64 + lane) * 8);
            }
            f32x4 qa = {bqr[h], bqr[h], bqr[h], bqr[h]};
            qa = MFMA(a0, c0, qa);
            qa = MFMA(a1, c1, qa);
            qa = MFMA(a2, c2, qa);
            const float qs = 0.25f * LOG2E;
            qpk[h * 2]     = (unsigned)f2bf(qa[0] * qs) | ((unsigned)f2bf(qa[1] * qs) << 16);
            qpk[h * 2 + 1] = (unsigned)f2bf(qa[2] * qs) | ((unsigned)f2bf(qa[3] * qs) << 16);
        }
    }
    __syncthreads();   // B2: all A_q reads done

    // ---- phase 2: kv half0 stage + MFMA ----
    #pragma unroll
    for (int t = 0; t < 3; ++t) {
        int base = (pi[t] * 8) * STR_A + pc[t];
        A[base]             = f2bf(pg[t][0].x); A[base + STR_A]     = f2bf(pg[t][0].y);
        A[base + 2 * STR_A] = f2bf(pg[t][0].z); A[base + 3 * STR_A] = f2bf(pg[t][0].w);
        A[base + 4 * STR_A] = f2bf(pg[t][1].x); A[base + 5 * STR_A] = f2bf(pg[t][1].y);
        A[base + 6 * STR_A] = f2bf(pg[t][1].z); A[base + 7 * STR_A] = f2bf(pg[t][1].w);
    }
    __syncthreads();   // B3: A_kv0 visible

    f32x4 accK[6], accV[6];
    #pragma unroll
    for (int n = 0; n < 6; ++n) {              // biases as MFMA C-seed
        accK[n] = {bkr[n], bkr[n], bkr[n], bkr[n]};
        accV[n] = {bvr[n], bvr[n], bvr[n], bvr[n]};
    }
    // half0 cluster: per kt, group-load 6 K-frags + 6 V-frags, then 12 MFMAs (deep vmcnt pipeline)
    #pragma unroll
    for (int kt = 0; kt < 3; ++kt) {
        short8 a = *(const short8*)(A + arow + kt * 32);
        short8 wkf[6], wvf[6];
        #pragma unroll
        for (int nt = 0; nt < 6; ++nt)
            wkf[nt] = *(const short8*)(ws + WS_WKT + (((kt * 6) + nt) * 64 + lane) * 8);
        #pragma unroll
        for (int nt = 0; nt < 6; ++nt)
            wvf[nt] = *(const short8*)(ws + WS_WVT + (((kt * 6) + nt) * 64 + lane) * 8);
        #pragma unroll
        for (int nt = 0; nt < 6; ++nt) accK[nt] = MFMA(a, wkf[nt], accK[nt]);
        #pragma unroll
        for (int nt = 0; nt < 6; ++nt) accV[nt] = MFMA(a, wvf[nt], accV[nt]);
    }
    // issue kv half1 loads AFTER the cluster (keeps peak VGPR < 128; latency covered by B4+stage)
    #pragma unroll
    for (int t = 0; t < 3; ++t) {
        const float* g = xkvb + (size_t)(96 + pc[t]) * 65536 + (h0 + pi[t]) * 256 + w0;
        pf[t][0] = *(const float4*)g; pf[t][1] = *(const float4*)(g + 4);
    }
    __syncthreads();   // B4: all A_kv0 reads done

    #pragma unroll
    for (int t = 0; t < 3; ++t) {
        int base = (pi[t] * 8) * STR_A + pc[t];
        A[base]             = f2bf(pf[t][0].x); A[base + STR_A]     = f2bf(pf[t][0].y);
        A[base + 2 * STR_A] = f2bf(pf[t][0].z); A[base + 3 * STR_A] = f2bf(pf[t][0].w);
        A[base + 4 * STR_A] = f2bf(pf[t][1].x); A[base + 5 * STR_A] = f2bf(pf[t][1].y);
        A[base + 6 * STR_A] = f2bf(pf[t][1].z); A[base + 7 * STR_A] = f2bf(pf[t][1].w);
    }
    __syncthreads();   // B5: A_kv1 visible

    #pragma unroll
    for (int kt = 0; kt < 3; ++kt) {
        short8 a = *(const short8*)(A + arow + kt * 32);
        short8 wkf[6], wvf[6];
        #pragma unroll
        for (int nt = 0; nt < 6; ++nt)
            wkf[nt] = *(const short8*)(ws + WS_WKT + ((((3 + kt) * 6) + nt) * 64 + lane) * 8);
        #pragma unroll
        for (int nt = 0; nt < 6; ++nt)
            wvf[nt] = *(const short8*)(ws + WS_WVT + ((((3 + kt) * 6) + nt) * 64 + lane) * 8);
        #pragma unroll
        for (int nt = 0; nt < 6; ++nt) accK[nt] = MFMA(a, wkf[nt], accK[nt]);
        #pragma unroll
        for (int nt = 0; nt < 6; ++nt) accV[nt] = MFMA(a, wvf[nt], accV[nt]);
    }
    // K16' into A region (own rows) + VT (token-contig per head)
    #pragma unroll
    for (int nt = 0; nt < 6; ++nt) {
        ushort* dk = A + (mt * 16 + quad * 4) * STR_A + nt * 16 + l15;
        ushort* dv = vt + nt * (16 * STR_VT) + l15 * STR_VT + (mt * 16 + quad * 4);
        #pragma unroll
        for (int r = 0; r < 4; ++r) {
            dk[r * STR_A] = f2bf(accK[nt][r]);
            dv[r]         = f2bf(accV[nt][r]);
        }
    }
    __syncthreads();   // B6: K16' + VT visible

    // ---- rel-bias indices (head-independent), packed u16 pairs ----
    const int qtok0 = mt * 16 + quad * 4;
    unsigned bidxp[4][2];
    #pragma unroll
    for (int nt = 0; nt < 4; ++nt) {
        int kt2 = nt * 16 + l15, i2 = kt2 >> 3, j2 = kt2 & 7;
        unsigned v[4];
        #pragma unroll
        for (int r = 0; r < 4; ++r) {
            int qt = qtok0 + r, i1 = qt >> 3, j1 = qt & 7;
            v[r] = (unsigned)(((i1 - i2 + 7) * 15 + (j1 - j2 + 7)) * 6);
        }
        bidxp[nt][0] = v[0] | (v[1] << 16);
        bidxp[nt][1] = v[2] | (v[3] << 16);
    }

    // ---- head loop, 2-head batches: chains of A and B interleave ----
    f32x4 accO[6];
    short8 zero8 = {};
    #pragma unroll
    for (int hp = 0; hp < 3; ++hp) {
        const int hA = hp * 2, hB = hA + 1;
        asm volatile("" ::: "memory");   // keep DS program order across ps/qsc alias
        unsigned wloA = qpk[hA * 2], whiA = qpk[hA * 2 + 1];
        unsigned wloB = qpk[hB * 2], whiB = qpk[hB * 2 + 1];
        ps[(quad * 4 + 0) * 24 + l15] = (ushort)wloA;
        ps[(quad * 4 + 1) * 24 + l15] = (ushort)(wloA >> 16);
        ps[(quad * 4 + 2) * 24 + l15] = (ushort)whiA;
        ps[(quad * 4 + 3) * 24 + l15] = (ushort)(whiA >> 16);
        ps[384 + (quad * 4 + 0) * 24 + l15] = (ushort)wloB;
        ps[384 + (quad * 4 + 1) * 24 + l15] = (ushort)(wloB >> 16);
        ps[384 + (quad * 4 + 2) * 24 + l15] = (ushort)whiB;
        ps[384 + (quad * 4 + 3) * 24 + l15] = (ushort)(whiB >> 16);
        short8 aqA = zero8, aqB = zero8;
        short8 kfA[4] = {zero8, zero8, zero8, zero8};
        short8 kfB[4] = {zero8, zero8, zero8, zero8};
        if (quad < 2) {
            aqA = *(const short8*)(ps + l15 * 24 + quad * 8);
            aqB = *(const short8*)(ps + 384 + l15 * 24 + quad * 8);
            #pragma unroll
            for (int nt = 0; nt < 4; ++nt) {
                kfA[nt] = *(const short8*)(A + (nt * 16 + l15) * STR_A + hA * 16 + quad * 8);
                kfB[nt] = *(const short8*)(A + (nt * 16 + l15) * STR_A + hB * 16 + quad * 8);
            }
        }
        f32x4 sA[4], sB[4];
        #pragma unroll
        for (int nt = 0; nt < 4; ++nt) {
            unsigned i01 = bidxp[nt][0], i23 = bidxp[nt][1];
            f32x4 c;
            c[0] = bf2f(biasl[(i01 & 0xFFFFu) + hA]); c[1] = bf2f(biasl[(i01 >> 16) + hA]);
            c[2] = bf2f(biasl[(i23 & 0xFFFFu) + hA]); c[3] = bf2f(biasl[(i23 >> 16) + hA]);
            sA[nt] = MFMA(aqA, kfA[nt], c);
        }
        #pragma unroll
        for (int nt = 0; nt < 4; ++nt) {
            unsigned i01 = bidxp[nt][0], i23 = bidxp[nt][1];
            f32x4 c;
            c[0] = bf2f(biasl[(i01 & 0xFFFFu) + hB]); c[1] = bf2f(biasl[(i01 >> 16) + hB]);
            c[2] = bf2f(biasl[(i23 & 0xFFFFu) + hB]); c[3] = bf2f(biasl[(i23 >> 16) + hB]);
            sB[nt] = MFMA(aqB, kfB[nt], c);
        }
        float prA[4][4], prB[4][4];
        softmax16(sA, prA);
        softmax16(sB, prB);
        // PV head A
        asm volatile("" ::: "memory");
        #pragma unroll
        for (int nt = 0; nt < 4; ++nt)
            #pragma unroll
            for (int r = 0; r < 4; ++r)
                ps[(quad * 4 + r) * 72 + nt * 16 + l15] = f2bf(prA[nt][r]);
        f32x4 oA = {};
        #pragma unroll
        for (int k2 = 0; k2 < 2; ++k2) {
            short8 ap  = *(const short8*)(ps + l15 * 72 + k2 * 32 + quad * 8);
            short8 bv8 = *(const short8*)(vt + hA * (16 * STR_VT) + l15 * STR_VT + k2 * 32 + quad * 8);
            oA = MFMA(ap, bv8, oA);
        }
        // PV head B
        asm volatile("" ::: "memory");
        #pragma unroll
        for (int nt = 0; nt < 4; ++nt)
            #pragma unroll
            for (int r = 0; r < 4; ++r)
                ps[(quad * 4 + r) * 72 + nt * 16 + l15] = f2bf(prB[nt][r]);
        f32x4 oB = {};
        #pragma unroll
        for (int k2 = 0; k2 < 2; ++k2) {
            short8 ap  = *(const short8*)(ps + l15 * 72 + k2 * 32 + quad * 8);
            short8 bv8 = *(const short8*)(vt + hB * (16 * STR_VT) + l15 * STR_VT + k2 * 32 + quad * 8);
            oB = MFMA(ap, bv8, oB);
        }
        accO[hA] = oA; accO[hB] = oB;
    }
    __syncthreads();   // B7: all K16' reads done before A-region reuse as obuf

    // ---- concat heads into obuf (own-wave rows) + out projection + store ----
    float bor_[6];
    #pragma unroll
    for (int h = 0; h < 6; ++h) bor_[h] = bo[h * 16 + l15];
    ushort* obuf = A;
    #pragma unroll
    for (int h = 0; h < 6; ++h)
        #pragma unroll
        for (int r = 0; r < 4; ++r)
            obuf[(mt * 16 + quad * 4 + r) * STR_A + h * 16 + l15] = f2bf(accO[h][r]);

    {
        int t0 = mt * 16 + quad * 4;
        int i = t0 >> 3, j0 = t0 & 7;
        // own-row reads: same-wave LDS ordering, no barrier needed; hoisted once
        short8 oa0 = *(const short8*)(obuf + arow);
        short8 oa1 = *(const short8*)(obuf + arow + 32);
        short8 oa2 = *(const short8*)(obuf + arow + 64);
        short8 wo0 = *(const short8*)(ws + WS_WOT + ((0) * 64 + lane) * 8);
        short8 wo1 = *(const short8*)(ws + WS_WOT + ((1) * 64 + lane) * 8);
        short8 wo2 = *(const short8*)(ws + WS_WOT + ((2) * 64 + lane) * 8);
        #pragma unroll
        for (int nt = 0; nt < 6; ++nt) {
            short8 c0 = wo0, c1 = wo1, c2 = wo2;
            if (nt < 5) {   // rotate next nt's frags
                wo0 = *(const short8*)(ws + WS_WOT + (((nt + 1) * 3 + 0) * 64 + lane) * 8);
                wo1 = *(const short8*)(ws + WS_WOT + (((nt + 1) * 3 + 1) * 64 + lane) * 8);
                wo2 = *(const short8*)(ws + WS_WOT + (((nt + 1) * 3 + 2) * 64 + lane) * 8);
            }
            f32x4 acc = {bor_[nt], bor_[nt], bor_[nt], bor_[nt]};
            acc = MFMA(oa0, c0, acc);
            acc = MFMA(oa1, c1, acc);
            acc = MFMA(oa2, c2, acc);
            int cout = nt * 16 + l15;
            float4 v4 = make_float4(acc[0], acc[1], acc[2], acc[3]);
            float* dst = out + (size_t)(b * 96 + cout) * 65536 + (h0 + i) * 256 + w0 + j0;
            *(float4*)dst = v4;
        }
    }
}

extern "C" void kernel_launch(void* const* d_in, const int* in_sizes, int n_in,
                              void* d_out, int out_size, void* d_ws, size_t ws_size,
                              hipStream_t stream) {
    const float* xq   = (const float*)d_in[0];
    const float* xkv  = (const float*)d_in[1];
    const float* Wq   = (const float*)d_in[2];
    const float* bq   = (const float*)d_in[3];
    const float* Wk   = (const float*)d_in[4];
    const float* bk   = (const float*)d_in[5];
    const float* Wv   = (const float*)d_in[6];
    const float* bv   = (const float*)d_in[7];
    const float* btab = (const float*)d_in[8];
    const float* Wo   = (const float*)d_in[9];
    const float* bo   = (const float*)d_in[10];
    ushort* ws = (ushort*)d_ws;
    float* out = (float*)d_out;

    hipLaunchKernelGGL(prep_weights, dim3((WS_TOTAL + 255) / 256), dim3(256), 0, stream,
                       Wq, Wk, Wv, Wo, btab, ws);
    hipLaunchKernelGGL(swin_attn, dim3(4096), dim3(256), 0, stream,
                       xq, xkv, bq, bk, bv, bo, ws, out);
}